// Round 11
// baseline (71.377 us; speedup 1.0000x reference)
//
#include <hip/hip_runtime.h>
#include <hip/hip_fp16.h>

// Flash-attention: B=16, Lq=Lk=2048, D=128, fp32 in/out, per-batch key masking.
// R11 = R7 structure with QW=32 (2 q-subtiles per wave), NW=2 (128 threads):
// each K/V ds_read feeds 2 MFMAs -> ~2x less LDS read traffic per unit work
// (theory: plateau at ~57us is LDS-BW bound from per-wave redundant tile reads).
// __syncthreads-per-tile staging (race-free), DMA from pre-swizzled f16 ws tiles,
// fixed-offset softmax. Grid 512, 2 blocks/CU, LDS 72KB.

typedef _Float16 f16x2 __attribute__((ext_vector_type(2)));
typedef _Float16 f16x4 __attribute__((ext_vector_type(4)));
typedef _Float16 f16x8 __attribute__((ext_vector_type(8)));
typedef __fp16   n16x2 __attribute__((ext_vector_type(2)));
typedef float    f32x4 __attribute__((ext_vector_type(4)));

#define LQ 2048
#define LK 2048
#define DIM 128
#define KT 64
#define NW 2                   // waves per block
#define TILEB 16384            // bytes per staged K or V tile (64x128 f16)
#define BATCHB (32 * TILEB)    // 512 KB per batch per tensor
#define CFIX 10.0f             // fixed softmax offset, log2 domain

__device__ __forceinline__ f16x2 cvt2(float a, float b) {
    n16x2 t = __builtin_amdgcn_cvt_pkrtz(a, b);
    return __builtin_bit_cast(f16x2, t);
}

__device__ __forceinline__ f16x8 pk8(float4 a, float4 b) {
    f16x2 p0 = cvt2(a.x, a.y), p1 = cvt2(a.z, a.w);
    f16x2 p2 = cvt2(b.x, b.y), p3 = cvt2(b.z, b.w);
    f16x8 r;
    r[0]=p0[0]; r[1]=p0[1]; r[2]=p1[0]; r[3]=p1[1];
    r[4]=p2[0]; r[5]=p2[1]; r[6]=p3[0]; r[7]=p3[1];
    return r;
}

__device__ __forceinline__ float fel(const float4& a, const float4& b, int d) {
    const float arr[8] = {a.x,a.y,a.z,a.w,b.x,b.y,b.z,b.w};
    return arr[d];
}

// K tile byte offset (within 16KB tile): row r (64), byte d (256/row)
__device__ __forceinline__ int k_off(int r, int dbyte) {
    return ((r << 8) + dbyte) ^ ((r & 7) << 4);
}
// V^T tile byte offset: d rows (128B each), key k (64); 16B-granule XOR swizzle
__device__ __forceinline__ int vt_off(int d, int k) {
    return d*128 + ((((k >> 3) ^ ((d ^ (d >> 3)) & 7)) << 4) + (k & 7) * 2);
}

// ---------------- pre-pass: K -> swizzled f16 tiles; V -> swizzled f16 V^T tiles ----
__global__ __launch_bounds__(256)
void prep_kernel(const float* __restrict__ K, const float* __restrict__ V,
                 char* __restrict__ Khs, char* __restrict__ Vts) {
    const int blk = blockIdx.x, tid = threadIdx.x;
    if (blk < 512) {
        __shared__ _Float16 t[64 * 136];
        const int b = blk >> 5, kt = blk & 31, k0 = kt * 64;
        const float* src = V + ((size_t)b * LK + k0) * DIM;
        #pragma unroll
        for (int i = 0; i < 4; ++i) {
            int e = i * 2048 + tid * 8;
            int row = e >> 7, d = e & 127;
            float4 a = *(const float4*)(src + row * DIM + d);
            float4 c = *(const float4*)(src + row * DIM + d + 4);
            *(f16x8*)(&t[row * 136 + d]) = pk8(a, c);
        }
        __syncthreads();
        char* out = Vts + (size_t)(b * 32 + kt) * TILEB;
        const int d = tid >> 1, khf = (tid & 1) * 4;
        const int sd = (d ^ (d >> 3)) & 7;
        #pragma unroll
        for (int c = 0; c < 4; ++c) {
            f16x8 w;
            #pragma unroll
            for (int j = 0; j < 8; ++j) w[j] = t[((khf + c) * 8 + j) * 136 + d];
            *(f16x8*)(out + d * 128 + (((khf + c) ^ sd) << 4)) = w;
        }
    } else {
        size_t e = ((size_t)(blk - 512) * 256 + tid) * 8;
        float4 a = *(const float4*)(K + e);
        float4 c = *(const float4*)(K + e + 4);
        size_t krow = e >> 7; int d0 = (int)(e & 127);
        size_t b = krow >> 11; int k = (int)(krow & 2047);
        char* out = Khs + (b * 32 + (k >> 6)) * TILEB;
        *(f16x8*)(out + k_off(k & 63, d0 << 1)) = pk8(a, c);
    }
}

// ---------------- main flash-attention kernel (128 threads, 2 waves) ----------------
// WS=true: DMA-staged pre-swizzled f16 tiles. WS=false: reg-staged fp32 fallback.
template<bool WS>
__global__ __launch_bounds__(128, 2)
void fa_kernel(const float* __restrict__ Qg, const float* __restrict__ Kg,
               const float* __restrict__ Vg, const char* __restrict__ Khs,
               const char* __restrict__ Vts, const int* __restrict__ VLg,
               float* __restrict__ Og)
{
    __shared__ __align__(16) char ldsbuf[2][2 * TILEB];   // [buf][ K 16KB | V 16KB ]
    __shared__ __align__(16) char ldsP[NW][2][2048];      // P[16 q][64 k] f16, swizzled

    const int tid = threadIdx.x, wv = tid >> 6, lane = tid & 63;
    const int lg = lane >> 4, ln = lane & 15;
    const int blk = blockIdx.x;
    const int b = 2 * (blk & 7) + ((blk >> 3) & 1);   // batch -> XCD affinity (R7 map)
    const int q0 = (blk >> 4) * 64 + wv * 32;         // 2 waves x 32 q-rows
    const int nvalid = VLg[b];                        // 1..2048
    const int nt = (nvalid + KT - 1) >> 6;            // skip fully-masked tiles (exact)
    const float SCL = 0.08838834764831845f * 1.44269504088896341f;

    const char*  Khb  = Khs + (size_t)b * BATCHB;
    const char*  Vtb  = Vts + (size_t)b * BATCHB;
    const float* Kb32 = Kg + (size_t)b * LK * DIM;
    const float* Vb32 = Vg + (size_t)b * LK * DIM;

    // per-wave DMA: 8x1KB for K half + 8x1KB for V half
    auto stage_dma = [&](int buf, int t) {
        const char* ks = Khb + (size_t)t * TILEB + wv * 8192 + lane * 16;
        const char* vs = Vtb + (size_t)t * TILEB + wv * 8192 + lane * 16;
        #pragma unroll
        for (int c = 0; c < 8; ++c)
            __builtin_amdgcn_global_load_lds(
                (const __attribute__((address_space(1))) unsigned*)(ks + c * 1024),
                (__attribute__((address_space(3))) unsigned*)&ldsbuf[buf][wv * 8192 + c * 1024],
                16, 0, 0);
        #pragma unroll
        for (int c = 0; c < 8; ++c)
            __builtin_amdgcn_global_load_lds(
                (const __attribute__((address_space(1))) unsigned*)(vs + c * 1024),
                (__attribute__((address_space(3))) unsigned*)&ldsbuf[buf][TILEB + wv * 8192 + c * 1024],
                16, 0, 0);
    };

    float4 ka[8], kb4[8], va[8], vb[8];   // fallback staging regs

    auto issue_fp32 = [&](int k0) {
        #pragma unroll
        for (int i = 0; i < 8; ++i) {
            int c = tid + i*128, row = c >> 4, d0 = (c & 15) * 8;
            const float* s = Kb32 + (size_t)(k0 + row)*DIM + d0;
            ka[i] = *(const float4*)s;  kb4[i] = *(const float4*)(s+4);
        }
        int kq = tid >> 4, d0 = (tid & 15) * 8;
        #pragma unroll
        for (int j = 0; j < 8; ++j) {
            const float* s = Vb32 + (size_t)(k0 + kq*8 + j)*DIM + d0;
            va[j] = *(const float4*)s;  vb[j] = *(const float4*)(s+4);
        }
    };

    auto swrite_fp32 = [&](int buf) {
        char* kb = &ldsbuf[buf][0];
        char* vb2 = &ldsbuf[buf][TILEB];
        #pragma unroll
        for (int i = 0; i < 8; ++i) {
            int c = tid + i*128, row = c >> 4, d0 = (c & 15) * 8;
            *(f16x8*)(kb + k_off(row, d0 << 1)) = pk8(ka[i], kb4[i]);
        }
        int kq = tid >> 4, d0 = (tid & 15) * 8;
        #pragma unroll
        for (int dd = 0; dd < 8; ++dd) {
            f16x2 w0 = cvt2(fel(va[0],vb[0],dd), fel(va[1],vb[1],dd));
            f16x2 w1 = cvt2(fel(va[2],vb[2],dd), fel(va[3],vb[3],dd));
            f16x2 w2 = cvt2(fel(va[4],vb[4],dd), fel(va[5],vb[5],dd));
            f16x2 w3 = cvt2(fel(va[6],vb[6],dd), fel(va[7],vb[7],dd));
            f16x8 w;
            w[0]=w0[0]; w[1]=w0[1]; w[2]=w1[0]; w[3]=w1[1];
            w[4]=w2[0]; w[5]=w2[1]; w[6]=w3[0]; w[7]=w3[1];
            *(f16x8*)(vb2 + vt_off(d0 + dd, kq*8)) = w;   // 8 keys, 16B aligned
        }
    };

    // ---- prologue: DMA/stage tile 0, load Q fragments (2 q-subtiles) ----
    if constexpr (WS) stage_dma(0, 0);
    else              issue_fp32(0);

    f16x8 qf[2][4];
    #pragma unroll
    for (int qs = 0; qs < 2; ++qs) {
        const float* qr = Qg + ((size_t)b*LQ + q0 + qs*16 + ln)*DIM + lg*8;
        #pragma unroll
        for (int dc = 0; dc < 4; ++dc) {
            float4 a = *(const float4*)(qr + dc*32);
            float4 c = *(const float4*)(qr + dc*32 + 4);
            a.x*=SCL; a.y*=SCL; a.z*=SCL; a.w*=SCL;
            c.x*=SCL; c.y*=SCL; c.z*=SCL; c.w*=SCL;
            qf[qs][dc] = pk8(a, c);
        }
    }

    if constexpr (!WS) swrite_fp32(0);
    __syncthreads();   // drains DMA (vmcnt) / publishes LDS writes

    f32x4 acc[2][8];
    #pragma unroll
    for (int qs = 0; qs < 2; ++qs)
        #pragma unroll
        for (int t = 0; t < 8; ++t) acc[qs][t] = (f32x4){0.f,0.f,0.f,0.f};
    float lrow[2] = {0.f, 0.f};

    char* pb0 = &ldsP[wv][0][0];
    char* pb1 = &ldsP[wv][1][0];
    int cur = 0;

    for (int t = 0; t < nt; ++t) {
        const int k0 = t * KT;
        const bool more = (t + 1 < nt);
        if (more) {
            if constexpr (WS) stage_dma(cur ^ 1, t + 1);   // full tile of compute to land
            else              issue_fp32(k0 + KT);
        }
        char* kbase = &ldsbuf[cur][0];
        char* vbase = &ldsbuf[cur][TILEB];

        // ---- swapped QK^T: each kf read feeds BOTH q-subtiles (2 MFMA / read) ----
        f32x4 s[2][4];
        #pragma unroll
        for (int qs = 0; qs < 2; ++qs)
            #pragma unroll
            for (int kc = 0; kc < 4; ++kc) s[qs][kc] = (f32x4){0.f,0.f,0.f,0.f};
        __builtin_amdgcn_s_setprio(1);
        #pragma unroll
        for (int kc = 0; kc < 4; ++kc) {
            #pragma unroll
            for (int dc = 0; dc < 4; ++dc) {
                f16x8 kf = *(const f16x8*)(kbase + k_off(kc*16 + ln, dc*64 + lg*16));
                s[0][kc] = __builtin_amdgcn_mfma_f32_16x16x32_f16(kf, qf[0][dc], s[0][kc], 0,0,0);
                s[1][kc] = __builtin_amdgcn_mfma_f32_16x16x32_f16(kf, qf[1][dc], s[1][kc], 0,0,0);
            }
        }
        __builtin_amdgcn_s_setprio(0);

        // ---- boundary mask (last tile only): key = k0 + kc*16 + 4*lg + r ----
        if (k0 + KT > nvalid) {
            #pragma unroll
            for (int kc = 0; kc < 4; ++kc)
                #pragma unroll
                for (int r = 0; r < 4; ++r)
                    if (k0 + kc*16 + 4*lg + r >= nvalid) { s[0][kc][r] = -1e30f; s[1][kc][r] = -1e30f; }
        }

        // ---- fixed-offset softmax: p = exp2(s - CFIX); no cross-lane ops ----
        #pragma unroll
        for (int qs = 0; qs < 2; ++qs) {
            char* pb = qs ? pb1 : pb0;
            float rs = 0.f;
            #pragma unroll
            for (int kc = 0; kc < 4; ++kc) {
                float p0 = __builtin_amdgcn_exp2f(s[qs][kc][0] - CFIX);  // masked -> exact 0
                float p1 = __builtin_amdgcn_exp2f(s[qs][kc][1] - CFIX);
                float p2 = __builtin_amdgcn_exp2f(s[qs][kc][2] - CFIX);
                float p3 = __builtin_amdgcn_exp2f(s[qs][kc][3] - CFIX);
                rs += (p0 + p1) + (p2 + p3);
                f16x2 lo = cvt2(p0, p1);
                f16x2 hi = cvt2(p2, p3);
                f16x4 w; w[0]=lo[0]; w[1]=lo[1]; w[2]=hi[0]; w[3]=hi[1];
                *(f16x4*)(pb + (ln << 7) + ((kc*32 + lg*8) ^ ((ln & 7) << 4))) = w;
            }
            lrow[qs] += rs;
        }

        asm volatile("s_waitcnt lgkmcnt(0)" ::: "memory");  // P writes -> af reads, same wave

        // ---- PV: each bf read feeds BOTH q-subtiles ----
        f16x8 af[2][2];
        #pragma unroll
        for (int qs = 0; qs < 2; ++qs) {
            char* pb = qs ? pb1 : pb0;
            #pragma unroll
            for (int kc2 = 0; kc2 < 2; ++kc2)
                af[qs][kc2] = *(const f16x8*)(pb + (ln << 7) + ((kc2*64 + lg*16) ^ ((ln & 7) << 4)));
        }
        __builtin_amdgcn_s_setprio(1);
        #pragma unroll
        for (int tt = 0; tt < 8; ++tt) {
            #pragma unroll
            for (int kc2 = 0; kc2 < 2; ++kc2) {
                f16x8 bf = *(const f16x8*)(vbase + vt_off(tt*16 + ln, kc2*32 + lg*8));
                acc[0][tt] = __builtin_amdgcn_mfma_f32_16x16x32_f16(af[0][kc2], bf, acc[0][tt], 0,0,0);
                acc[1][tt] = __builtin_amdgcn_mfma_f32_16x16x32_f16(af[1][kc2], bf, acc[1][tt], 0,0,0);
            }
        }
        __builtin_amdgcn_s_setprio(0);

        if (more) {
            if constexpr (!WS) swrite_fp32(cur ^ 1);
            __syncthreads();   // DMA/writes of t+1 complete; all reads of cur done
            cur ^= 1;
        }
    }

    // ---- epilogue: reduce l per q-subtile, store O ----
    #pragma unroll
    for (int qs = 0; qs < 2; ++qs) {
        float l = lrow[qs];
        l += __shfl_xor(l, 16);
        l += __shfl_xor(l, 32);
        float linv = 1.f / l;
        #pragma unroll
        for (int r = 0; r < 4; ++r) {
            float lr = __shfl(linv, 4*lg + r);
            float* orow = Og + ((size_t)b*LQ + q0 + qs*16 + 4*lg + r)*DIM + ln;
            #pragma unroll
            for (int tt = 0; tt < 8; ++tt) orow[tt*16] = acc[qs][tt][r] * lr;
        }
    }
}

extern "C" void kernel_launch(void* const* d_in, const int* in_sizes, int n_in,
                              void* d_out, int out_size, void* d_ws, size_t ws_size,
                              hipStream_t stream) {
    const float* Q  = (const float*)d_in[0];
    const float* K  = (const float*)d_in[1];
    const float* V  = (const float*)d_in[2];
    const int*   VL = (const int*)d_in[3];
    float* O = (float*)d_out;

    const size_t need = (size_t)16 * BATCHB * 2;   // Khs + Vts = 16 MB
    if (ws_size >= need) {   // deterministic: depends only on ws_size
        char* Khs = (char*)d_ws;
        char* Vts = Khs + (size_t)16 * BATCHB;
        prep_kernel<<<dim3(512 + 2048), dim3(256), 0, stream>>>(K, V, Khs, Vts);
        fa_kernel<true><<<dim3(512), dim3(128), 0, stream>>>(Q, K, V, Khs, Vts, VL, O);
    } else {
        fa_kernel<false><<<dim3(512), dim3(128), 0, stream>>>(Q, K, V, nullptr, nullptr, VL, O);
    }
}